// Round 11
// baseline (759.946 us; speedup 1.0000x reference)
//
#include <hip/hip_runtime.h>

#define T_DATA 200000
#define E_NO 400
#define I_NO 100
#define SUB_NO 20
#define N_BASIS 20
#define T_NO 200

typedef unsigned short u16;
typedef unsigned int u32;

// ---- workspace layout (ws_size measured ~1.28 GB in R9; we use ~16.1 MB) ----
#define WS_K4    0                       // 4000 float4 = 64000
#define WS_HIST2 64000                   // 200 float2
#define WS_LISTS 65600                   // 542 int -> end 67768
#define WS_SYNE  131072                  // 20*200000 u16 = 8e6
#define WS_SYNI  (WS_SYNE + 8000000)     // end ~16.1 MB

__device__ __forceinline__ u16 f2bf(float f) {
    union { float f; u32 u; } v; v.f = f;
    u32 u = v.u;
    u32 lsb = (u >> 16) & 1u;
    u += 0x7fffu + lsb;            // RNE
    return (u16)(u >> 16);
}
__device__ __forceinline__ float bf2f(u16 b) {
    union { u32 u; float f; } v; v.u = ((u32)b) << 16; return v.f;
}
__device__ __forceinline__ void unpack8(uint4 u, float* x) {
    union { u32 u; float f; } c;
    c.u = u.x << 16;          x[0] = c.f;
    c.u = u.x & 0xffff0000u;  x[1] = c.f;
    c.u = u.y << 16;          x[2] = c.f;
    c.u = u.y & 0xffff0000u;  x[3] = c.f;
    c.u = u.z << 16;          x[4] = c.f;
    c.u = u.z & 0xffff0000u;  x[5] = c.f;
    c.u = u.w << 16;          x[6] = c.f;
    c.u = u.w & 0xffff0000u;  x[7] = c.f;
}
__device__ __forceinline__ float fast_tanh(float x) {
    x = fminf(fmaxf(x, -15.f), 15.f);
    float e = __expf(2.f * x);
    return 1.f - 2.f / (e + 1.f);
}
__device__ __forceinline__ float fast_sigmoid(float x) {
    x = fminf(fmaxf(x, -30.f), 30.f);
    return 1.f / (1.f + __expf(-x));
}

// ============================================================================
// k_setup: 22 blocks. 0..19 subunit filters -> k4/outF; 20 hist kernels;
// 21 assignment lists. (R10-proven)
// ============================================================================
__global__ __launch_bounds__(256) void k_setup(
    const float* __restrict__ Wns, const float* __restrict__ Tau,
    const float* __restrict__ Del, const float* __restrict__ Wsyns,
    const float* __restrict__ HwS, const float* __restrict__ HwNS,
    const float* __restrict__ Cse, const float* __restrict__ Csi,
    float4* __restrict__ k4, float2* __restrict__ hist2,
    int* __restrict__ lists, float* __restrict__ outF)
{
    __shared__ float cb[N_BASIS * T_NO];
    __shared__ int easn[E_NO], iasn[I_NO];
    __shared__ int cnt[2 * SUB_NO], cur[2 * SUB_NO];
    const int tid = threadIdx.x;
    const int b = blockIdx.x;
    const float PI = 3.14159265358979323846f;

    if (b == 21) {
        if (tid < 2 * SUB_NO) cnt[tid] = 0;
        __syncthreads();
        for (int j = tid; j < E_NO; j += 256) {
            int a = 0;
            for (int s = 0; s < SUB_NO; ++s)
                if (Cse[s * E_NO + j] > 0.5f) a = s;
            easn[j] = a;
            atomicAdd(&cnt[a], 1);
        }
        for (int j = tid; j < I_NO; j += 256) {
            int a = 0;
            for (int s = 0; s < SUB_NO; ++s)
                if (Csi[s * I_NO + j] > 0.5f) a = s;
            iasn[j] = a;
            atomicAdd(&cnt[SUB_NO + a], 1);
        }
        __syncthreads();
        if (tid == 0) {
            int aE = 0, aI = 0;
            for (int s = 0; s < SUB_NO; ++s) {
                lists[s] = aE;      cur[s] = aE;           aE += cnt[s];
                lists[21 + s] = aI; cur[SUB_NO + s] = aI;  aI += cnt[SUB_NO + s];
            }
            lists[20] = aE;
            lists[41] = aI;
        }
        __syncthreads();
        for (int j = tid; j < E_NO; j += 256) {
            int p = atomicAdd(&cur[easn[j]], 1);
            lists[42 + p] = j;
        }
        for (int j = tid; j < I_NO; j += 256) {
            int p = atomicAdd(&cur[SUB_NO + iasn[j]], 1);
            lists[442 + p] = j;
        }
        return;
    }

    for (int it = tid; it < N_BASIS * T_NO; it += 256) {
        int bb = it / T_NO, j = it - bb * T_NO;
        float phi = 1.57079632679489662f * (float)bb;
        float raw = 5.0f * logf((float)j + 1.0f);
        float v = 0.f;
        if (raw >= phi - PI && raw <= phi + PI) v = 0.5f * cosf(raw - phi) + 0.5f;
        cb[it] = v;
    }
    __syncthreads();

    if (b < 20) {
        const int s = b;
        if (tid < T_NO) {
            const int j = tid;
            float tau_e = Tau[s * 2 + 0]; tau_e *= tau_e;
            float tau_i = Tau[s * 2 + 1]; tau_i *= tau_i;
            float de = Del[s * 2 + 0], di = Del[s * 2 + 1];
            float we = Wns[s * 2 + 0]; we *= we;
            float wi = Wns[s * 2 + 1]; wi *= wi;
            float te = fmaxf((float)j - de, 0.f) / tau_e;
            float ti = fmaxf((float)j - di, 0.f) / tau_i;
            float eNs = te * expf(-te) * we;
            float iNs = -ti * expf(-ti) * wi;
            float eS = 0.f, iS = 0.f;
            for (int bb = 0; bb < N_BASIS; ++bb) {
                float w0 = Wsyns[(s * N_BASIS + bb) * 2 + 0];
                float w1 = Wsyns[(s * N_BASIS + bb) * 2 + 1];
                float c = cb[bb * T_NO + j];
                eS += w0 * w0 * c;
                iS -= w1 * w1 * c;
            }
            int it = s * T_NO + j;
            k4[it] = make_float4(eNs, iNs, eS, iS);
            outF[it]         = eNs;
            outF[4000 + it]  = iNs;
            outF[8000 + it]  = eS;
            outF[12000 + it] = iS;
        }
    } else {
        if (tid < T_NO) {
            const int j = tid;
            float hn = 0.f, hs = 0.f;
            for (int bb = 0; bb < N_BASIS; ++bb) {
                float c = cb[bb * T_NO + j];
                hn += HwNS[bb] * c;
                hs += HwS[bb] * c;
            }
            hist2[j] = make_float2(hn, hs);
            outF[16000 + j] = hn;
            outF[16200 + j] = hs;
        }
    }
}

// ============================================================================
// k_spikes: 4 x 16-t tiles per block (64 t), register-prefetch pipelined.
// Exact-fit grid (3125 blocks) -> NO bounds checks in loads. Coalesced u32
// write-out via LDS out-buffer. 38.8 KB LDS -> 4 blocks/CU.
// ============================================================================
#define AR 16
__global__ __launch_bounds__(256) void k_spikes(
    const float* __restrict__ Se, const float* __restrict__ Si,
    const int* __restrict__ listsg,
    u16* __restrict__ synEb, u16* __restrict__ synIb)
{
    __shared__ __align__(16) float tE[AR * 404];     // stride 101 float4
    __shared__ __align__(16) float tI[AR * 104];     // stride 26 float4
    __shared__ __align__(16) u16 outE[SUB_NO * 64];
    __shared__ __align__(16) u16 outI[SUB_NO * 64];
    __shared__ int leo[21], lio[21];
    __shared__ u16 lei[E_NO], lii[I_NO];
    const int tid = threadIdx.x;
    const int t0 = blockIdx.x * 64;

    if (tid < 21) { leo[tid] = listsg[tid]; lio[tid] = listsg[21 + tid]; }
    for (int k = tid; k < E_NO; k += 256) lei[k] = (u16)listsg[42 + k];
    for (int k = tid; k < I_NO; k += 256) lii[k] = (u16)listsg[442 + k];

    const float4* Se4 = (const float4*)Se;
    const float4* Si4 = (const float4*)Si;
    float4 pre[8];

#define SLOAD(IT)                                                            \
    {                                                                        \
        _Pragma("unroll")                                                    \
        for (int q = 0; q < 8; ++q) {                                        \
            int k = tid + q * 256;                                           \
            if (k < 1600) {                                                  \
                int r = k / 100, c = k - r * 100;                            \
                pre[q] = Se4[(size_t)(t0 + (IT) * AR + r) * 100 + c];        \
            } else if (k < 2000) {                                           \
                int kk = k - 1600;                                           \
                int r = kk / 25, c = kk - r * 25;                            \
                pre[q] = Si4[(size_t)(t0 + (IT) * AR + r) * 25 + c];         \
            }                                                                \
        }                                                                    \
    }

#define SSTORE()                                                             \
    {                                                                        \
        _Pragma("unroll")                                                    \
        for (int q = 0; q < 8; ++q) {                                        \
            int k = tid + q * 256;                                           \
            if (k < 1600) {                                                  \
                int r = k / 100, c = k - r * 100;                            \
                ((float4*)tE)[r * 101 + c] = pre[q];                         \
            } else if (k < 2000) {                                           \
                int kk = k - 1600;                                           \
                int r = kk / 25, c = kk - r * 25;                            \
                ((float4*)tI)[r * 26 + c] = pre[q];                          \
            }                                                                \
        }                                                                    \
    }

#define SGATHER(IT)                                                          \
    {                                                                        \
        for (int task = tid; task < 640; task += 256) {                      \
            if (task < 320) {                                                \
                int s = task >> 4, r = task & 15;                            \
                int k0 = leo[s], k1 = leo[s + 1];                            \
                const float* row = tE + r * 404;                             \
                float a0 = 0.f, a1 = 0.f, a2 = 0.f, a3 = 0.f;                \
                int k = k0;                                                  \
                for (; k + 4 <= k1; k += 4) {                                \
                    a0 += row[lei[k]];                                       \
                    a1 += row[lei[k + 1]];                                   \
                    a2 += row[lei[k + 2]];                                   \
                    a3 += row[lei[k + 3]];                                   \
                }                                                            \
                for (; k < k1; ++k) a0 += row[lei[k]];                       \
                outE[s * 64 + (IT) * AR + r] = f2bf((a0 + a1) + (a2 + a3));  \
            } else {                                                         \
                int tk = task - 320;                                         \
                int s = tk >> 4, r = tk & 15;                                \
                const float* row = tI + r * 104;                             \
                float a = 0.f;                                               \
                for (int k = lio[s]; k < lio[s + 1]; ++k) a += row[lii[k]];  \
                outI[s * 64 + (IT) * AR + r] = f2bf(a);                      \
            }                                                                \
        }                                                                    \
    }

    SLOAD(0);
    SSTORE();
    __syncthreads();
#pragma unroll 1
    for (int it = 1; it < 4; ++it) {
        SLOAD(it);        // issue next tile's global loads (overlap gather)
        SGATHER(it - 1);
        __syncthreads();
        SSTORE();
        __syncthreads();
    }
    SGATHER(3);
    __syncthreads();

    // coalesced write-out: 2 arrays x 20 rows x 32 u32
    for (int q = tid; q < 1280; q += 256) {
        int arr = (q >= 640) ? 1 : 0;
        int qq = q - arr * 640;
        int s = qq >> 5, c = qq & 31;
        u32 val = ((const u32*)(arr ? outI : outE))[s * 32 + c];
        *((u32*)((arr ? synIb : synEb) + (size_t)s * T_DATA + t0) + c) = val;
    }
}

// ============================================================================
// k_convtree: 512 t x all-20-subunit conv (+ hist-of-Z as stage 5, wave 0,
// pre-shifted Z row) + tree epilogue. 391 blocks, ~80 KB LDS -> 2/CU.
// ============================================================================
#define TT 512
#define WROW 712
__global__ __launch_bounds__(256) void k_convtree(
    const u16* __restrict__ synEb, const u16* __restrict__ synIb,
    const float* __restrict__ Z,
    const float4* __restrict__ k4g, const float2* __restrict__ hist2g,
    const int* __restrict__ Cden,
    const float* __restrict__ WsubNS, const float* __restrict__ WsubS,
    const float* __restrict__ Vo, const float* __restrict__ ThNS,
    const float* __restrict__ ThS,
    float* __restrict__ outV, float* __restrict__ outZ)
{
    __shared__ __align__(16) u16 sEw[21 * WROW];      // 29904 B (row20 = Z, shifted)
    __shared__ __align__(16) u16 sIw[21 * WROW];      // 29904 B (row20 = 0)
    __shared__ __align__(16) float4 k4c[4 * T_NO];    // 12800 B per-stage kernels
    __shared__ __align__(16) float2 hout[TT];         // 4096 B hist results
    __shared__ float AS[SUB_NO][SUB_NO], AN[SUB_NO][SUB_NO];  // 3200 B
    __shared__ float ths[SUB_NO], thn[SUB_NO];
    __shared__ float wn20s, vos;
    const int tid = threadIdx.x;
    const int t0 = blockIdx.x * TT;
    const int W0 = t0 - 200;

    // ---- stage syn windows (rows 0..19) from ws ----
    for (int q = tid; q < 3560; q += 256) {
        int arr = (q >= 1780) ? 1 : 0;
        int qq = q - arr * 1780;
        int row = qq / 89, c = qq - row * 89;
        const u16* src = (arr ? synIb : synEb) + (size_t)row * T_DATA;
        u16* dst = (arr ? sIw : sEw) + row * WROW + c * 8;
        int gg = W0 + c * 8;
        if (gg >= 0 && gg + 8 <= T_DATA) {
            *(uint4*)dst = *(const uint4*)(src + gg);
        } else {
            for (int e = 0; e < 8; ++e) {
                int t = gg + e;
                dst[e] = (t >= 0 && t < T_DATA) ? src[t] : (u16)0;
            }
        }
    }
    // ---- row 20: E = Z shifted by -1 (local i <-> Z[t0-201+i]); I = zeros ----
    for (int c = tid; c < 89; c += 256) {
        int gg = t0 - 201 + c * 8;
        u16 zb[8];
        for (int e = 0; e < 8; ++e) {
            int t = gg + e;
            zb[e] = (t >= 0 && t < T_DATA) ? f2bf(Z[t]) : (u16)0;
        }
        u32 w0 = (u32)zb[0] | ((u32)zb[1] << 16);
        u32 w1 = (u32)zb[2] | ((u32)zb[3] << 16);
        u32 w2 = (u32)zb[4] | ((u32)zb[5] << 16);
        u32 w3 = (u32)zb[6] | ((u32)zb[7] << 16);
        *(uint4*)(sEw + 20 * WROW + c * 8) = make_uint4(w0, w1, w2, w3);
        *(uint4*)(sIw + 20 * WROW + c * 8) = make_uint4(0, 0, 0, 0);
    }
    // ---- tree params ----
    for (int k = tid; k < SUB_NO * SUB_NO; k += 256) {
        int idx = k / SUB_NO, c = k - idx * SUB_NO;
        float m = (float)Cden[k];
        float wsv = WsubS[c];
        float wnv = WsubNS[c];
        AS[idx][c] = m * wsv * wsv;
        AN[idx][c] = m * wnv * wnv;
    }
    if (tid < SUB_NO) { ths[tid] = ThS[tid]; thn[tid] = ThNS[tid]; }
    if (tid == 0) {
        float w = WsubNS[0];
        wn20s = w * w;
        vos = Vo[0];
    }

    const int wv = tid >> 6;          // wave index (wave-uniform)
    const int slot = tid & 63;
    const int bT = slot * 8;

    // ---- conv stages: g=0..4 rows 4g..4g+3; g=5 hist (wave 0, row 20) ----
#pragma unroll 1
    for (int g = 0; g < 6; ++g) {
        if (g > 0) __syncthreads();             // prior stage k4c reads done
        if (g < 5) {
            for (int q = tid; q < 800; q += 256) {
                int su = q / 200, j = q - su * 200;
                k4c[q] = k4g[(g * 4 + su) * T_NO + j];
            }
        } else {
            for (int q = tid; q < 200; q += 256) {
                float2 h = hist2g[q];
                k4c[q] = make_float4(h.x, 0.f, h.y, 0.f);
            }
        }
        __syncthreads();                        // k4c (and, at g=0, windows) ready

        if (g < 5 || wv == 0) {
            const int row = (g < 5) ? (g * 4 + wv) : 20;
            const u16* rowE = sEw + row * WROW;
            const u16* rowI = sIw + row * WROW;
            float aN[8], aS2[8];
#pragma unroll
            for (int m = 0; m < 8; ++m) { aN[m] = 0.f; aS2[m] = 0.f; }

#pragma unroll 1
            for (int jj = 0; jj <= 192; jj += 8) {
                const int p = bT + 192 - jj;     // mult of 8 -> 16B aligned
                float xe[16], xi[16];
                uint4 eA = *(const uint4*)(rowE + p);
                uint4 eB = *(const uint4*)(rowE + p + 8);
                uint4 iA = *(const uint4*)(rowI + p);
                uint4 iB = *(const uint4*)(rowI + p + 8);
                unpack8(eA, xe); unpack8(eB, xe + 8);
                unpack8(iA, xi); unpack8(iB, xi + 8);
#pragma unroll
                for (int k = 0; k < 8; ++k) {
                    float4 kk = k4c[wv * T_NO + jj + k];   // wv=0 when g==5
#pragma unroll
                    for (int m = 0; m < 8; ++m) {
                        float e = xe[m + 8 - k];
                        float ii = xi[m + 8 - k];
                        aN[m]  = fmaf(e, kk.x, fmaf(ii, kk.y, aN[m]));
                        aS2[m] = fmaf(e, kk.z, fmaf(ii, kk.w, aS2[m]));
                    }
                }
            }

            if (g < 5) {
                // in-place writeback: local index = output t-offset in [0,512)
                u32 w0 = (u32)f2bf(aN[0]) | ((u32)f2bf(aN[1]) << 16);
                u32 w1 = (u32)f2bf(aN[2]) | ((u32)f2bf(aN[3]) << 16);
                u32 w2 = (u32)f2bf(aN[4]) | ((u32)f2bf(aN[5]) << 16);
                u32 w3 = (u32)f2bf(aN[6]) | ((u32)f2bf(aN[7]) << 16);
                *(uint4*)(sEw + row * WROW + bT) = make_uint4(w0, w1, w2, w3);
                u32 v0 = (u32)f2bf(aS2[0]) | ((u32)f2bf(aS2[1]) << 16);
                u32 v1 = (u32)f2bf(aS2[2]) | ((u32)f2bf(aS2[3]) << 16);
                u32 v2 = (u32)f2bf(aS2[4]) | ((u32)f2bf(aS2[5]) << 16);
                u32 v3 = (u32)f2bf(aS2[6]) | ((u32)f2bf(aS2[7]) << 16);
                *(uint4*)(sIw + row * WROW + bT) = make_uint4(v0, v1, v2, v3);
            } else {
#pragma unroll
                for (int m = 0; m < 8; ++m)
                    hout[bT + m] = make_float2(aN[m], aS2[m]);
            }
        }
    }
    __syncthreads();

    // ---- tree recursion + f32 outputs, 2 t per thread ----
#pragma unroll 1
    for (int m = 0; m < 2; ++m) {
        const int i = tid * 2 + m;
        const int t = t0 + i;
        float2 hf = hout[i];

        float vs[SUB_NO], vn[SUB_NO];
#pragma unroll
        for (int c = 0; c < SUB_NO; ++c) { vs[c] = 0.f; vn[c] = 0.f; }
#pragma unroll
        for (int idx = SUB_NO - 1; idx >= 1; --idx) {
            float cs = 0.f, cn = 0.f;
#pragma unroll
            for (int c = 0; c < SUB_NO; ++c) {
                cs = fmaf(AS[idx][c], vs[c], cs);
                cn = fmaf(AN[idx][c], vn[c], cn);
            }
            float synS_v = bf2f(sIw[idx * WROW + i]);
            float synN_v = bf2f(sEw[idx * WROW + i]);
            vs[idx] = fast_tanh(synS_v + cs + ths[idx]);
            vn[idx] = fast_tanh(synN_v + cn + thn[idx]);
        }
        float cs0 = 0.f, cn0 = 0.f;
#pragma unroll
        for (int c = 0; c < SUB_NO; ++c) {
            cs0 = fmaf(AS[0][c], vs[c], cs0);
            cn0 = fmaf(AN[0][c], vn[c], cn0);
        }
        float s0  = fast_sigmoid(hf.y + bf2f(sIw[i]) + cs0 + ths[0]);
        float ns0 = fast_tanh(hf.x + bf2f(sEw[i]) + cn0 + thn[0]);

        if (t < T_DATA) {
            outV[t] = ns0 * wn20s + vos;
            outZ[t] = s0;
        }
    }
}

// ============================================================================
extern "C" void kernel_launch(void* const* d_in, const int* in_sizes, int n_in,
                              void* d_out, int out_size, void* d_ws, size_t ws_size,
                              hipStream_t stream)
{
    const float* Se    = (const float*)d_in[0];
    const float* Si    = (const float*)d_in[1];
    const float* Z     = (const float*)d_in[2];
    const int*   Cden  = (const int*)d_in[3];
    const float* Cse   = (const float*)d_in[4];
    const float* Csi   = (const float*)d_in[5];
    const float* Wns   = (const float*)d_in[6];
    const float* Tau   = (const float*)d_in[7];
    const float* Del   = (const float*)d_in[8];
    const float* Wsyns = (const float*)d_in[9];
    const float* WsubNS= (const float*)d_in[10];
    const float* WsubS = (const float*)d_in[11];
    const float* Vo    = (const float*)d_in[12];
    const float* ThNS  = (const float*)d_in[13];
    const float* ThS   = (const float*)d_in[14];
    const float* HwS   = (const float*)d_in[15];
    const float* HwNS  = (const float*)d_in[16];

    char* ws = (char*)d_ws;
    float4* k4    = (float4*)(ws + WS_K4);
    float2* hist2 = (float2*)(ws + WS_HIST2);
    int*    lists = (int*)(ws + WS_LISTS);
    u16*    synEb = (u16*)(ws + WS_SYNE);
    u16*    synIb = (u16*)(ws + WS_SYNI);

    float* outV = (float*)d_out;
    float* outZ = outV + T_DATA;
    float* outF = outV + 2 * T_DATA;

    k_setup<<<22, 256, 0, stream>>>(Wns, Tau, Del, Wsyns, HwS, HwNS, Cse, Csi,
                                    k4, hist2, lists, outF);
    k_spikes<<<T_DATA / 64, 256, 0, stream>>>(Se, Si, lists, synEb, synIb);
    k_convtree<<<(T_DATA + TT - 1) / TT, 256, 0, stream>>>(
        synEb, synIb, Z, k4, hist2, Cden, WsubNS, WsubS, Vo, ThNS, ThS,
        outV, outZ);
}

// Round 12
// 630.317 us; speedup vs baseline: 1.2057x; 1.2057x over previous
//
#include <hip/hip_runtime.h>

#define T_DATA 200000
#define E_NO 400
#define I_NO 100
#define SUB_NO 20
#define N_BASIS 20
#define T_NO 200

typedef unsigned short u16;
typedef unsigned int u32;

// ---- workspace layout (ws_size ~1.28 GB measured; we use ~33.7 MB) ----
#define WS_K4    0                       // 4000 float4 = 64000
#define WS_HIST2 64000                   // 200 float2
#define WS_LISTS 65600                   // 542 int -> end 67768
#define WS_SYNE  131072                  // 20*200000 u16 = 8e6
#define WS_SYNI  (WS_SYNE + 8000000)
#define WS_SNS   (WS_SYNI + 8000000)
#define WS_SS    (WS_SNS + 8000000)
#define WS_HF    (WS_SS + 8000000)       // 200000 float2 = 1.6e6

__device__ __forceinline__ u16 f2bf(float f) {
    union { float f; u32 u; } v; v.f = f;
    u32 u = v.u;
    u32 lsb = (u >> 16) & 1u;
    u += 0x7fffu + lsb;            // RNE
    return (u16)(u >> 16);
}
__device__ __forceinline__ float bf2f(u16 b) {
    union { u32 u; float f; } v; v.u = ((u32)b) << 16; return v.f;
}
__device__ __forceinline__ void unpack8(uint4 u, float* x) {
    union { u32 u; float f; } c;
    c.u = u.x << 16;          x[0] = c.f;
    c.u = u.x & 0xffff0000u;  x[1] = c.f;
    c.u = u.y << 16;          x[2] = c.f;
    c.u = u.y & 0xffff0000u;  x[3] = c.f;
    c.u = u.z << 16;          x[4] = c.f;
    c.u = u.z & 0xffff0000u;  x[5] = c.f;
    c.u = u.w << 16;          x[6] = c.f;
    c.u = u.w & 0xffff0000u;  x[7] = c.f;
}
__device__ __forceinline__ float fast_tanh(float x) {
    x = fminf(fmaxf(x, -15.f), 15.f);
    float e = __expf(2.f * x);
    return 1.f - 2.f / (e + 1.f);
}
__device__ __forceinline__ float fast_sigmoid(float x) {
    x = fminf(fmaxf(x, -30.f), 30.f);
    return 1.f / (1.f + __expf(-x));
}

// ============================================================================
// k_setup: 22 blocks. 0..19 subunit filters -> k4/outF; 20 hist kernels;
// 21 assignment lists. (R10-proven)
// ============================================================================
__global__ __launch_bounds__(256) void k_setup(
    const float* __restrict__ Wns, const float* __restrict__ Tau,
    const float* __restrict__ Del, const float* __restrict__ Wsyns,
    const float* __restrict__ HwS, const float* __restrict__ HwNS,
    const float* __restrict__ Cse, const float* __restrict__ Csi,
    float4* __restrict__ k4, float2* __restrict__ hist2,
    int* __restrict__ lists, float* __restrict__ outF)
{
    __shared__ float cb[N_BASIS * T_NO];
    __shared__ int easn[E_NO], iasn[I_NO];
    __shared__ int cnt[2 * SUB_NO], cur[2 * SUB_NO];
    const int tid = threadIdx.x;
    const int b = blockIdx.x;
    const float PI = 3.14159265358979323846f;

    if (b == 21) {
        if (tid < 2 * SUB_NO) cnt[tid] = 0;
        __syncthreads();
        for (int j = tid; j < E_NO; j += 256) {
            int a = 0;
            for (int s = 0; s < SUB_NO; ++s)
                if (Cse[s * E_NO + j] > 0.5f) a = s;
            easn[j] = a;
            atomicAdd(&cnt[a], 1);
        }
        for (int j = tid; j < I_NO; j += 256) {
            int a = 0;
            for (int s = 0; s < SUB_NO; ++s)
                if (Csi[s * I_NO + j] > 0.5f) a = s;
            iasn[j] = a;
            atomicAdd(&cnt[SUB_NO + a], 1);
        }
        __syncthreads();
        if (tid == 0) {
            int aE = 0, aI = 0;
            for (int s = 0; s < SUB_NO; ++s) {
                lists[s] = aE;      cur[s] = aE;           aE += cnt[s];
                lists[21 + s] = aI; cur[SUB_NO + s] = aI;  aI += cnt[SUB_NO + s];
            }
            lists[20] = aE;
            lists[41] = aI;
        }
        __syncthreads();
        for (int j = tid; j < E_NO; j += 256) {
            int p = atomicAdd(&cur[easn[j]], 1);
            lists[42 + p] = j;
        }
        for (int j = tid; j < I_NO; j += 256) {
            int p = atomicAdd(&cur[SUB_NO + iasn[j]], 1);
            lists[442 + p] = j;
        }
        return;
    }

    for (int it = tid; it < N_BASIS * T_NO; it += 256) {
        int bb = it / T_NO, j = it - bb * T_NO;
        float phi = 1.57079632679489662f * (float)bb;
        float raw = 5.0f * logf((float)j + 1.0f);
        float v = 0.f;
        if (raw >= phi - PI && raw <= phi + PI) v = 0.5f * cosf(raw - phi) + 0.5f;
        cb[it] = v;
    }
    __syncthreads();

    if (b < 20) {
        const int s = b;
        if (tid < T_NO) {
            const int j = tid;
            float tau_e = Tau[s * 2 + 0]; tau_e *= tau_e;
            float tau_i = Tau[s * 2 + 1]; tau_i *= tau_i;
            float de = Del[s * 2 + 0], di = Del[s * 2 + 1];
            float we = Wns[s * 2 + 0]; we *= we;
            float wi = Wns[s * 2 + 1]; wi *= wi;
            float te = fmaxf((float)j - de, 0.f) / tau_e;
            float ti = fmaxf((float)j - di, 0.f) / tau_i;
            float eNs = te * expf(-te) * we;
            float iNs = -ti * expf(-ti) * wi;
            float eS = 0.f, iS = 0.f;
            for (int bb = 0; bb < N_BASIS; ++bb) {
                float w0 = Wsyns[(s * N_BASIS + bb) * 2 + 0];
                float w1 = Wsyns[(s * N_BASIS + bb) * 2 + 1];
                float c = cb[bb * T_NO + j];
                eS += w0 * w0 * c;
                iS -= w1 * w1 * c;
            }
            int it = s * T_NO + j;
            k4[it] = make_float4(eNs, iNs, eS, iS);
            outF[it]         = eNs;
            outF[4000 + it]  = iNs;
            outF[8000 + it]  = eS;
            outF[12000 + it] = iS;
        }
    } else {
        if (tid < T_NO) {
            const int j = tid;
            float hn = 0.f, hs = 0.f;
            for (int bb = 0; bb < N_BASIS; ++bb) {
                float c = cb[bb * T_NO + j];
                hn += HwNS[bb] * c;
                hs += HwS[bb] * c;
            }
            hist2[j] = make_float2(hn, hs);
            outF[16000 + j] = hn;
            outF[16200 + j] = hs;
        }
    }
}

// ============================================================================
// k_spikes: wave-autonomous. Each wave owns 4 t in a private LDS region;
// no block barrier in the hot path (one cheap list barrier before the global
// loads; wave cross-lane LDS visibility via s_waitcnt lgkmcnt(0)).
// 12500 blocks, 33.8 KB LDS -> 4 blocks/CU = 16 independent waves/CU.
// ============================================================================
__global__ __launch_bounds__(256) void k_spikes(
    const float* __restrict__ Se, const float* __restrict__ Si,
    const int* __restrict__ listsg,
    u16* __restrict__ synEb, u16* __restrict__ synIb)
{
    __shared__ __align__(16) float tE[4][4 * 404];   // per-wave, row stride 404
    __shared__ __align__(16) float tI[4][4 * 104];   // per-wave, row stride 104
    __shared__ int leo[21], lio[21];
    __shared__ u16 lei[E_NO], lii[I_NO];
    const int tid = threadIdx.x;
    const int wv = tid >> 6, lane = tid & 63;
    const int t0 = (blockIdx.x * 4 + wv) * 4;        // this wave's 4 timesteps

    if (tid < 21) { leo[tid] = listsg[tid]; lio[tid] = listsg[21 + tid]; }
    for (int k = tid; k < E_NO; k += 256) lei[k] = (u16)listsg[42 + k];
    for (int k = tid; k < I_NO; k += 256) lii[k] = (u16)listsg[442 + k];
    __syncthreads();                    // lists only — cheap (no vmem in flight)

    // wave-private coalesced loads: E = 400 float4 linear, I = 100 float4
    const float4* Se4 = (const float4*)(Se + (size_t)t0 * E_NO);
    const float4* Si4 = (const float4*)(Si + (size_t)t0 * I_NO);
    float4 ve[7];
#pragma unroll
    for (int i = 0; i < 7; ++i) {
        int k = lane + i * 64;
        if (k < 400) ve[i] = Se4[k];
    }
    float4 vi0 = make_float4(0.f, 0.f, 0.f, 0.f);
    float4 vi1 = make_float4(0.f, 0.f, 0.f, 0.f);
    if (lane < 100) vi0 = Si4[lane];
    if (lane + 64 < 100) vi1 = Si4[lane + 64];

    // store to private LDS (padded row strides break bank alignment)
#pragma unroll
    for (int i = 0; i < 7; ++i) {
        int k = lane + i * 64;
        if (k < 400) {
            int r = k / 100, c = k - r * 100;
            *(float4*)&tE[wv][r * 404 + c * 4] = ve[i];
        }
    }
    if (lane < 100) {
        int r = lane / 25, c = lane - r * 25;
        *(float4*)&tI[wv][r * 104 + c * 4] = vi0;
    }
    if (lane + 64 < 100) {
        int k = lane + 64;
        int r = k / 25, c = k - r * 25;
        *(float4*)&tI[wv][r * 104 + c * 4] = vi1;
    }
    // intra-wave cross-lane LDS visibility without __syncthreads
    asm volatile("s_waitcnt lgkmcnt(0)" ::: "memory");

    // gather: 160 tasks (80 E + 80 I) over 64 lanes, 3 passes
#pragma unroll 1
    for (int p = 0; p < 3; ++p) {
        int task = p * 64 + lane;
        if (task < 80) {
            int s = task >> 2, r = task & 3;
            int k0 = leo[s], k1 = leo[s + 1];
            const float* row = &tE[wv][r * 404];
            float a0 = 0.f, a1 = 0.f, a2 = 0.f, a3 = 0.f;
            int k = k0;
            for (; k + 4 <= k1; k += 4) {
                a0 += row[lei[k]];
                a1 += row[lei[k + 1]];
                a2 += row[lei[k + 2]];
                a3 += row[lei[k + 3]];
            }
            for (; k < k1; ++k) a0 += row[lei[k]];
            synEb[(size_t)s * T_DATA + t0 + r] = f2bf((a0 + a1) + (a2 + a3));
        } else if (task < 160) {
            int tt = task - 80;
            int s = tt >> 2, r = tt & 3;
            const float* row = &tI[wv][r * 104];
            float a = 0.f;
            for (int k = lio[s]; k < lio[s + 1]; ++k) a += row[lii[k]];
            synIb[(size_t)s * T_DATA + t0 + r] = f2bf(a);
        }
    }
}

// ============================================================================
// k_conv (R10-proven): depthwise conv. blockIdx.y 0..4 = 4 subunits each;
// 5 = hist-of-Z (hist[t] = conv(Z)[t-1] -> hfilt f32). 24 KB LDS -> 6/CU.
// ============================================================================
#define TT 512
#define WROW 712
__global__ __launch_bounds__(256) void k_conv(
    const u16* __restrict__ synEb, const u16* __restrict__ synIb,
    const float* __restrict__ Z,
    const float4* __restrict__ k4g, const float2* __restrict__ hist2g,
    u16* __restrict__ synNSb, u16* __restrict__ synSb,
    float2* __restrict__ hfilt)
{
    __shared__ __align__(16) u16 wE[4 * WROW];
    __shared__ __align__(16) u16 wI[4 * WROW];
    __shared__ __align__(16) float4 k4l[4 * T_NO];
    const int tid = threadIdx.x;
    const int t0 = blockIdx.x * TT;
    const int g  = blockIdx.y;
    const int W0 = t0 - 200;

    if (g < 5) {
        for (int q = tid; q < 712; q += 256) {
            int arr = (q >= 356) ? 1 : 0;
            int qq = q - arr * 356;
            int row = qq / 89, c = qq - row * 89;
            int s = g * 4 + row;
            const u16* src = (arr ? synIb : synEb) + (size_t)s * T_DATA;
            u16* dst = (arr ? wI : wE) + row * WROW + c * 8;
            int gg = W0 + c * 8;
            if (gg >= 0 && gg + 8 <= T_DATA) {
                *(uint4*)dst = *(const uint4*)(src + gg);
            } else {
                for (int e = 0; e < 8; ++e) {
                    int t = gg + e;
                    dst[e] = (t >= 0 && t < T_DATA) ? src[t] : (u16)0;
                }
            }
        }
        for (int q = tid; q < 800; q += 256) {
            int su = q / 200, j = q - su * 200;
            k4l[q] = k4g[(g * 4 + su) * T_NO + j];
        }
    } else {
        for (int q = tid; q < 623; q += 256) {
            if (q < 356) ((uint4*)wI)[q] = make_uint4(0, 0, 0, 0);
            else         ((uint4*)wE)[q - 356 + 89] = make_uint4(0, 0, 0, 0);
        }
        for (int c = tid; c < 89; c += 256) {
            int gg = W0 + c * 8;
            u16 zb[8];
            for (int e = 0; e < 8; ++e) {
                int t = gg + e;
                zb[e] = (t >= 0 && t < T_DATA) ? f2bf(Z[t]) : (u16)0;
            }
            u32 w0 = (u32)zb[0] | ((u32)zb[1] << 16);
            u32 w1 = (u32)zb[2] | ((u32)zb[3] << 16);
            u32 w2 = (u32)zb[4] | ((u32)zb[5] << 16);
            u32 w3 = (u32)zb[6] | ((u32)zb[7] << 16);
            *(uint4*)(wE + c * 8) = make_uint4(w0, w1, w2, w3);
        }
        for (int q = tid; q < 800; q += 256) {
            int su = q / 200, j = q - su * 200;
            float4 v = make_float4(0.f, 0.f, 0.f, 0.f);
            if (su == 0) {
                float2 h = hist2g[j];
                v = make_float4(h.x, 0.f, h.y, 0.f);
            }
            k4l[q] = v;
        }
    }
    __syncthreads();

    const int wv = tid >> 6;
    const int slot = tid & 63;
    const int bT = slot * 8;
    const u16* rowE = wE + wv * WROW;
    const u16* rowI = wI + wv * WROW;

    float aN[8], aS2[8];
#pragma unroll
    for (int m = 0; m < 8; ++m) { aN[m] = 0.f; aS2[m] = 0.f; }

#pragma unroll 1
    for (int jj = 0; jj <= 192; jj += 8) {
        const int p = bT + 192 - jj;
        float xe[16], xi[16];
        uint4 eA = *(const uint4*)(rowE + p);
        uint4 eB = *(const uint4*)(rowE + p + 8);
        uint4 iA = *(const uint4*)(rowI + p);
        uint4 iB = *(const uint4*)(rowI + p + 8);
        unpack8(eA, xe); unpack8(eB, xe + 8);
        unpack8(iA, xi); unpack8(iB, xi + 8);
#pragma unroll
        for (int k = 0; k < 8; ++k) {
            float4 kk = k4l[wv * T_NO + jj + k];
#pragma unroll
            for (int m = 0; m < 8; ++m) {
                float e = xe[m + 8 - k];
                float ii = xi[m + 8 - k];
                aN[m]  = fmaf(e, kk.x, fmaf(ii, kk.y, aN[m]));
                aS2[m] = fmaf(e, kk.z, fmaf(ii, kk.w, aS2[m]));
            }
        }
    }

    if (g < 5) {
        const int s = g * 4 + wv;
        const int t = t0 + bT;
        u32 w0 = (u32)f2bf(aN[0]) | ((u32)f2bf(aN[1]) << 16);
        u32 w1 = (u32)f2bf(aN[2]) | ((u32)f2bf(aN[3]) << 16);
        u32 w2 = (u32)f2bf(aN[4]) | ((u32)f2bf(aN[5]) << 16);
        u32 w3 = (u32)f2bf(aN[6]) | ((u32)f2bf(aN[7]) << 16);
        u32 v0 = (u32)f2bf(aS2[0]) | ((u32)f2bf(aS2[1]) << 16);
        u32 v1 = (u32)f2bf(aS2[2]) | ((u32)f2bf(aS2[3]) << 16);
        u32 v2 = (u32)f2bf(aS2[4]) | ((u32)f2bf(aS2[5]) << 16);
        u32 v3 = (u32)f2bf(aS2[6]) | ((u32)f2bf(aS2[7]) << 16);
        if (t + 8 <= T_DATA) {
            *(uint4*)(synNSb + (size_t)s * T_DATA + t) = make_uint4(w0, w1, w2, w3);
            *(uint4*)(synSb  + (size_t)s * T_DATA + t) = make_uint4(v0, v1, v2, v3);
        } else if (t < T_DATA) {
            for (int m = 0; m < 8 && t + m < T_DATA; ++m) {
                synNSb[(size_t)s * T_DATA + t + m] = f2bf(aN[m]);
                synSb[(size_t)s * T_DATA + t + m] = f2bf(aS2[m]);
            }
        }
    } else if (wv == 0) {
#pragma unroll
        for (int m = 0; m < 8; ++m) {
            int tt = t0 + bT + m + 1;
            if (tt < T_DATA) hfilt[tt] = make_float2(aN[m], aS2[m]);
        }
        if (blockIdx.x == 0 && tid == 0) hfilt[0] = make_float2(0.f, 0.f);
    }
}

// ============================================================================
// k_tree (R10-proven): tree recursion + f32 outputs (hist precomputed).
// ============================================================================
#define CT 256
__global__ __launch_bounds__(256) void k_tree(
    const u16* __restrict__ synNSb, const u16* __restrict__ synSb,
    const float2* __restrict__ hfilt,
    const int* __restrict__ Cden,
    const float* __restrict__ WsubNS, const float* __restrict__ WsubS,
    const float* __restrict__ Vo, const float* __restrict__ ThNS,
    const float* __restrict__ ThS,
    float* __restrict__ outV, float* __restrict__ outZ)
{
    __shared__ __align__(16) u16 lNS[SUB_NO * CT];
    __shared__ __align__(16) u16 lS[SUB_NO * CT];
    __shared__ float AS[SUB_NO][SUB_NO], AN[SUB_NO][SUB_NO];
    __shared__ float ths[SUB_NO], thn[SUB_NO];
    __shared__ float wn20s, vos;
    const int tid = threadIdx.x;
    const int t0 = blockIdx.x * CT;

    for (int q = tid; q < 1280; q += 256) {
        int arr = (q >= 640) ? 1 : 0;
        int qq = q - arr * 640;
        int row = qq >> 5, c = qq & 31;
        const u16* src = (arr ? synSb : synNSb) + (size_t)row * T_DATA;
        u16* dst = (arr ? lS : lNS) + row * CT + c * 8;
        int gg = t0 + c * 8;
        if (gg + 8 <= T_DATA) {
            *(uint4*)dst = *(const uint4*)(src + gg);
        } else {
            for (int e = 0; e < 8; ++e) {
                int t = gg + e;
                dst[e] = (t < T_DATA) ? src[t] : (u16)0;
            }
        }
    }
    for (int k = tid; k < SUB_NO * SUB_NO; k += 256) {
        int idx = k / SUB_NO, c = k - idx * SUB_NO;
        float m = (float)Cden[k];
        float wsv = WsubS[c];
        float wnv = WsubNS[c];
        AS[idx][c] = m * wsv * wsv;
        AN[idx][c] = m * wnv * wnv;
    }
    if (tid < SUB_NO) { ths[tid] = ThS[tid]; thn[tid] = ThNS[tid]; }
    if (tid == 0) {
        float w = WsubNS[0];
        wn20s = w * w;
        vos = Vo[0];
    }
    __syncthreads();

    const int t = t0 + tid;
    float2 hf = make_float2(0.f, 0.f);
    if (t < T_DATA) hf = hfilt[t];

    float vs[SUB_NO], vn[SUB_NO];
#pragma unroll
    for (int c = 0; c < SUB_NO; ++c) { vs[c] = 0.f; vn[c] = 0.f; }
#pragma unroll
    for (int idx = SUB_NO - 1; idx >= 1; --idx) {
        float cs = 0.f, cn = 0.f;
#pragma unroll
        for (int c = 0; c < SUB_NO; ++c) {
            cs = fmaf(AS[idx][c], vs[c], cs);
            cn = fmaf(AN[idx][c], vn[c], cn);
        }
        float synS_v = bf2f(lS[idx * CT + tid]);
        float synN_v = bf2f(lNS[idx * CT + tid]);
        vs[idx] = fast_tanh(synS_v + cs + ths[idx]);
        vn[idx] = fast_tanh(synN_v + cn + thn[idx]);
    }
    float cs0 = 0.f, cn0 = 0.f;
#pragma unroll
    for (int c = 0; c < SUB_NO; ++c) {
        cs0 = fmaf(AS[0][c], vs[c], cs0);
        cn0 = fmaf(AN[0][c], vn[c], cn0);
    }
    float s0  = fast_sigmoid(hf.y + bf2f(lS[tid]) + cs0 + ths[0]);
    float ns0 = fast_tanh(hf.x + bf2f(lNS[tid]) + cn0 + thn[0]);

    if (t < T_DATA) {
        outV[t] = ns0 * wn20s + vos;
        outZ[t] = s0;
    }
}

// ============================================================================
extern "C" void kernel_launch(void* const* d_in, const int* in_sizes, int n_in,
                              void* d_out, int out_size, void* d_ws, size_t ws_size,
                              hipStream_t stream)
{
    const float* Se    = (const float*)d_in[0];
    const float* Si    = (const float*)d_in[1];
    const float* Z     = (const float*)d_in[2];
    const int*   Cden  = (const int*)d_in[3];
    const float* Cse   = (const float*)d_in[4];
    const float* Csi   = (const float*)d_in[5];
    const float* Wns   = (const float*)d_in[6];
    const float* Tau   = (const float*)d_in[7];
    const float* Del   = (const float*)d_in[8];
    const float* Wsyns = (const float*)d_in[9];
    const float* WsubNS= (const float*)d_in[10];
    const float* WsubS = (const float*)d_in[11];
    const float* Vo    = (const float*)d_in[12];
    const float* ThNS  = (const float*)d_in[13];
    const float* ThS   = (const float*)d_in[14];
    const float* HwS   = (const float*)d_in[15];
    const float* HwNS  = (const float*)d_in[16];

    char* ws = (char*)d_ws;
    float4* k4    = (float4*)(ws + WS_K4);
    float2* hist2 = (float2*)(ws + WS_HIST2);
    int*    lists = (int*)(ws + WS_LISTS);
    u16*    synEb = (u16*)(ws + WS_SYNE);
    u16*    synIb = (u16*)(ws + WS_SYNI);
    u16*    synNSb= (u16*)(ws + WS_SNS);
    u16*    synSb = (u16*)(ws + WS_SS);
    float2* hfilt = (float2*)(ws + WS_HF);

    float* outV = (float*)d_out;
    float* outZ = outV + T_DATA;
    float* outF = outV + 2 * T_DATA;

    k_setup<<<22, 256, 0, stream>>>(Wns, Tau, Del, Wsyns, HwS, HwNS, Cse, Csi,
                                    k4, hist2, lists, outF);
    k_spikes<<<T_DATA / 16, 256, 0, stream>>>(Se, Si, lists, synEb, synIb);
    dim3 gc((T_DATA + TT - 1) / TT, 6);
    k_conv<<<gc, 256, 0, stream>>>(synEb, synIb, Z, k4, hist2,
                                   synNSb, synSb, hfilt);
    k_tree<<<(T_DATA + CT - 1) / CT, 256, 0, stream>>>(
        synNSb, synSb, hfilt, Cden, WsubNS, WsubS, Vo, ThNS, ThS,
        outV, outZ);
}